// Round 2
// baseline (680.384 us; speedup 1.0000x reference)
//
#include <hip/hip_runtime.h>

using f32x4 = float    __attribute__((ext_vector_type(4)));
using f16x8 = _Float16 __attribute__((ext_vector_type(8)));

__device__ __forceinline__ void gload_lds16(const void* g, void* l) {
    __builtin_amdgcn_global_load_lds(
        (__attribute__((address_space(1))) void*)(void*)g,
        (__attribute__((address_space(3))) void*)l, 16, 0, 0);
}

// ---------------- fp32 -> fp16 elementwise convert (8 elems/thread) ---------
__global__ __launch_bounds__(256) void k_cvt_x(
    const float* __restrict__ in, _Float16* __restrict__ out) {
    int i = (blockIdx.x * 256 + threadIdx.x) * 8;
    f32x4 a = *(const f32x4*)(in + i);
    f32x4 b = *(const f32x4*)(in + i + 4);
    f16x8 o;
    #pragma unroll
    for (int j = 0; j < 4; ++j) { o[j] = (_Float16)a[j]; o[j + 4] = (_Float16)b[j]; }
    *(f16x8*)(out + i) = o;
}

// ---------------- fp32 in [R][C] -> fp16 out[c][r] (convert + transpose) ----
__global__ __launch_bounds__(256) void k_cvtT(
    const float* __restrict__ in, _Float16* __restrict__ out, int R, int C) {
    __shared__ _Float16 tile[32][33];
    int c0 = blockIdx.x * 32, r0 = blockIdx.y * 32;
    int tx = threadIdx.x & 31, ty = threadIdx.x >> 5;
    #pragma unroll
    for (int i = ty; i < 32; i += 8)
        tile[i][tx] = (_Float16)in[(size_t)(r0 + i) * C + c0 + tx];
    __syncthreads();
    #pragma unroll
    for (int i = ty; i < 32; i += 8)
        out[(size_t)(c0 + i) * R + r0 + tx] = tile[tx][i];
}

// ---------------- fp16 transpose: out[c][r] = in[r][c], in is [R][C] --------
__global__ __launch_bounds__(256) void k_transpose16(
    const _Float16* __restrict__ in, _Float16* __restrict__ out, int R, int C) {
    __shared__ _Float16 tile[32][33];
    int c0 = blockIdx.x * 32, r0 = blockIdx.y * 32;
    int tx = threadIdx.x & 31, ty = threadIdx.x >> 5;
    #pragma unroll
    for (int i = ty; i < 32; i += 8)
        tile[i][tx] = in[(size_t)(r0 + i) * C + c0 + tx];
    __syncthreads();
    #pragma unroll
    for (int i = ty; i < 32; i += 8)
        out[(size_t)(c0 + i) * R + r0 + tx] = tile[tx][i];
}

// ---------------- m97-style fp16 GEMM, C = A @ Bt^T -------------------------
// A: [M,K] fp16 row-major, Bt: [N,K] fp16 row-major. BM=128 fixed.
// OM: 0 = fp32 store, 1 = fp16 store, 2 = fp32 store + fp32 residual add
template<int OM, int BN>
__global__ __launch_bounds__(256, 2) void k_gemm_bt(
    const _Float16* __restrict__ A, int lda,
    const _Float16* __restrict__ Bt, int ldb,
    void* __restrict__ Cp, int ldc, int K,
    const float* __restrict__ R) {
    constexpr int BM  = 128;
    constexpr int NI  = BN / 32;          // 16x16 tiles per wave in N
    constexpr int NCH = (BM + BN) / 16;   // 1KB staging chunks
    __shared__ _Float16 As[BM * 32];
    __shared__ _Float16 Bs[BN * 32];
    const int row0 = blockIdx.y * BM, col0 = blockIdx.x * BN;
    const int tid = threadIdx.x, w = tid >> 6, lane = tid & 63;
    const int wm = w >> 1, wn = w & 1;
    const int lrow = lane & 15, quad = lane >> 4;
    const int r16 = lane >> 2;            // row within 16-row chunk
    const int kc  = (lane & 3) * 8;       // fp16 col offset (16B segment)
    f32x4 acc[4][NI] = {};

    for (int k0 = 0; k0 < K; k0 += 32) {
        #pragma unroll
        for (int i = 0; i < NCH / 4; ++i) {
            int c = w + i * 4;            // wave-uniform chunk id
            if (c < BM / 16) {
                gload_lds16(A + (size_t)(row0 + c * 16 + r16) * lda + (k0 + kc),
                            As + c * 512);
            } else {
                int c2 = c - BM / 16;
                gload_lds16(Bt + (size_t)(col0 + c2 * 16 + r16) * ldb + (k0 + kc),
                            Bs + c2 * 512);
            }
        }
        __syncthreads();
        f16x8 af[4], bfr[NI];
        #pragma unroll
        for (int i = 0; i < 4; ++i)
            af[i] = *(const f16x8*)(As + (wm * 64 + i * 16 + lrow) * 32 + quad * 8);
        #pragma unroll
        for (int i = 0; i < NI; ++i)
            bfr[i] = *(const f16x8*)(Bs + (wn * (BN / 2) + i * 16 + lrow) * 32 + quad * 8);
        #pragma unroll
        for (int mi = 0; mi < 4; ++mi)
            #pragma unroll
            for (int ni = 0; ni < NI; ++ni)
                acc[mi][ni] = __builtin_amdgcn_mfma_f32_16x16x32_f16(
                    af[mi], bfr[ni], acc[mi][ni], 0, 0, 0);
        __syncthreads();
    }
    // epilogue: C/D layout col=lane&15, row=quad*4+reg
    #pragma unroll
    for (int mi = 0; mi < 4; ++mi) {
        #pragma unroll
        for (int ni = 0; ni < NI; ++ni) {
            int col = col0 + wn * (BN / 2) + ni * 16 + lrow;
            #pragma unroll
            for (int r = 0; r < 4; ++r) {
                int row = row0 + wm * 64 + mi * 16 + quad * 4 + r;
                float v = acc[mi][ni][r];
                if constexpr (OM == 0) {
                    ((float*)Cp)[(size_t)row * ldc + col] = v;
                } else if constexpr (OM == 1) {
                    ((_Float16*)Cp)[(size_t)row * ldc + col] = (_Float16)v;
                } else {
                    v += R[(size_t)row * ldc + col];
                    ((float*)Cp)[(size_t)row * ldc + col] = v;
                }
            }
        }
    }
}

// ---------------- split WhWs -> Wh(fp16), T = tanh(Wh+Ws+bias) (fp16) -------
__global__ __launch_bounds__(256) void k_tanh_split(
    const float* __restrict__ WhWs, _Float16* __restrict__ T,
    _Float16* __restrict__ Wh,
    const float* __restrict__ aw, const float* __restrict__ ab) {
    int i = blockIdx.x * 256 + threadIdx.x;      // over 8192*512
    float bias = aw[0] + ab[0];
    int row = i >> 9, col = i & 511;
    float wh  = WhWs[(size_t)row * 1024 + col];
    float wsv = WhWs[(size_t)row * 1024 + 512 + col];
    Wh[i] = (_Float16)wh;
    T[i]  = (_Float16)tanhf(wh + wsv + bias);
}

// ---------------- row softmax in place: S fp16 -> P fp16 --------------------
__global__ __launch_bounds__(256) void k_softmax_rows(
    _Float16* __restrict__ S, int N) {
    const int row = blockIdx.x;
    _Float16* prow = S + (size_t)row * N;
    const int t = threadIdx.x;
    float v[32];
    #pragma unroll
    for (int it = 0; it < 4; ++it) {
        f16x8 h = *(const f16x8*)(prow + (it * 256 + t) * 8);
        #pragma unroll
        for (int j = 0; j < 8; ++j) v[it * 8 + j] = (float)h[j];
    }
    float m = v[0];
    #pragma unroll
    for (int j = 1; j < 32; ++j) m = fmaxf(m, v[j]);
    #pragma unroll
    for (int off = 32; off > 0; off >>= 1) m = fmaxf(m, __shfl_xor(m, off));
    __shared__ float red[8];
    const int wid = t >> 6, lane = t & 63;
    if (lane == 0) red[wid] = m;
    __syncthreads();
    m = fmaxf(fmaxf(red[0], red[1]), fmaxf(red[2], red[3]));
    float l = 0.f;
    #pragma unroll
    for (int j = 0; j < 32; ++j) l += __expf(v[j] - m);
    #pragma unroll
    for (int off = 32; off > 0; off >>= 1) l += __shfl_xor(l, off);
    if (lane == 0) red[4 + wid] = l;
    __syncthreads();
    float rl = 1.f / (red[4] + red[5] + red[6] + red[7]);
    #pragma unroll
    for (int it = 0; it < 4; ++it) {
        f16x8 pk;
        #pragma unroll
        for (int j = 0; j < 8; ++j)
            pk[j] = (_Float16)(__expf(v[it * 8 + j] - m) * rl);
        *(f16x8*)(prow + (it * 256 + t) * 8) = pk;
    }
}

// ---------------- per-column sum / sumsq over rows (atomics) ----------------
__global__ __launch_bounds__(256) void k_col_stats(
    const float* __restrict__ outf, float* __restrict__ colsum,
    float* __restrict__ colsq) {
    int t = threadIdx.x;
    int r0 = blockIdx.x * 128;
    float s0 = 0, q0 = 0, s1 = 0, q1 = 0;
    for (int r = 0; r < 128; ++r) {
        const float* p = outf + (size_t)(r0 + r) * 512;
        float a = p[t], b = p[t + 256];
        s0 += a; q0 += a * a; s1 += b; q1 += b * b;
    }
    atomicAdd(&colsum[t], s0);       atomicAdd(&colsq[t], q0);
    atomicAdd(&colsum[t + 256], s1); atomicAdd(&colsq[t + 256], q1);
}

// ---------------- batchnorm (no affine) + leaky relu -> fp32 ----------------
__global__ __launch_bounds__(256) void k_bn_lrelu(
    const float* __restrict__ outf, const float* __restrict__ colsum,
    const float* __restrict__ colsq, float* __restrict__ out) {
    int i = blockIdx.x * 256 + threadIdx.x;
    int c = i & 511;
    constexpr float rN = 1.f / 8192.f;
    float mean = colsum[c] * rN;
    float var  = colsq[c] * rN - mean * mean;
    float y = (outf[i] - mean) * rsqrtf(var + 1e-5f);
    y = (y >= 0.f) ? y : 0.01f * y;
    out[i] = y;
}

extern "C" void kernel_launch(void* const* d_in, const int* in_sizes, int n_in,
                              void* d_out, int out_size, void* d_ws, size_t ws_size,
                              hipStream_t stream) {
    const float* X  = (const float*)d_in[0];  // [8192,512] fp32
    // d_in[1] = adj, unused
    const float* W  = (const float*)d_in[2];  // [512,1024] fp32
    const float* aw = (const float*)d_in[3];
    const float* ab = (const float*)d_in[4];
    float* out = (float*)d_out;               // [8192,512] fp32

    char* ws = (char*)d_ws;
    _Float16* Xh   = (_Float16*)(ws + 0x0);         //  8 MB  [8192,512]
    _Float16* Wt   = (_Float16*)(ws + 0x800000);    //  1 MB  W^T [1024,512]
    float*    WhWs = (float*)   (ws + 0x900000);    // 32 MB  [8192,1024] fp32
    _Float16* T    = (_Float16*)(ws + 0x2900000);   //  8 MB  [8192,512]
    _Float16* Whh  = (_Float16*)(ws + 0x3100000);   //  8 MB  [8192,512]
    _Float16* WhT  = (_Float16*)(ws + 0x3900000);   //  8 MB  [512,8192]
    _Float16* S    = (_Float16*)(ws + 0x4100000);   // 128 MB [8192,8192] fp16
    float*    outf = (float*)   (ws + 0xC100000);   // 16 MB  [8192,512] fp32
    float*    cs   = (float*)   (ws + 0xD100000);   //  2 KB
    float*    cq   = (float*)   (ws + 0xD100800);   //  2 KB

    // 0. Xh = fp16(X)
    k_cvt_x<<<dim3((8192 * 512) / 2048), 256, 0, stream>>>(X, Xh);
    // 1. Wt = fp16(W^T)  (W is [512, 1024])
    k_cvtT<<<dim3(1024 / 32, 512 / 32), 256, 0, stream>>>(W, Wt, 512, 1024);
    // 2. WhWs = Xh @ W  (fp32 out)  M=8192 N=1024 K=512
    k_gemm_bt<0, 128><<<dim3(1024 / 128, 8192 / 128), 256, 0, stream>>>(
        Xh, 512, Wt, 512, WhWs, 1024, 512, nullptr);
    // 3. Whh (fp16) and T = tanh(Wh + Ws + bias) (fp16)
    k_tanh_split<<<dim3((8192 * 512) / 256), 256, 0, stream>>>(WhWs, T, Whh, aw, ab);
    // 4. WhT = Whh^T
    k_transpose16<<<dim3(512 / 32, 8192 / 32), 256, 0, stream>>>(Whh, WhT, 8192, 512);
    // 5. S = T @ Whh^T  (fp16 out)  M=8192 N=8192 K=512
    k_gemm_bt<1, 128><<<dim3(8192 / 128, 8192 / 128), 256, 0, stream>>>(
        T, 512, Whh, 512, S, 8192, 512, nullptr);
    // 6. row softmax in place: S -> P (fp16)
    k_softmax_rows<<<dim3(8192), 256, 0, stream>>>(S, 8192);
    // 7. outf = P @ Whh + X  (fp32)  M=8192 N=512 K=8192; Bt = WhT
    k_gemm_bt<2, 64><<<dim3(512 / 64, 8192 / 128), 256, 0, stream>>>(
        S, 8192, WhT, 8192, outf, 512, 8192, X);
    // 8-9. batch norm stats + normalize + leaky relu
    hipMemsetAsync(cs, 0, 4096, stream);
    k_col_stats<<<dim3(64), 256, 0, stream>>>(outf, cs, cq);
    k_bn_lrelu<<<dim3((8192 * 512) / 256), 256, 0, stream>>>(outf, cs, cq, out);
}

// Round 3
// 572.098 us; speedup vs baseline: 1.1893x; 1.1893x over previous
//
#include <hip/hip_runtime.h>

using f32x4 = float    __attribute__((ext_vector_type(4)));
using f16x8 = _Float16 __attribute__((ext_vector_type(8)));

__device__ __forceinline__ void gload_lds16(const void* g, void* l) {
    __builtin_amdgcn_global_load_lds(
        (__attribute__((address_space(1))) void*)(void*)g,
        (__attribute__((address_space(3))) void*)l, 16, 0, 0);
}

// ---------------- fp32 -> fp16 elementwise convert (8 elems/thread) ---------
__global__ __launch_bounds__(256) void k_cvt_x(
    const float* __restrict__ in, _Float16* __restrict__ out) {
    int i = (blockIdx.x * 256 + threadIdx.x) * 8;
    f32x4 a = *(const f32x4*)(in + i);
    f32x4 b = *(const f32x4*)(in + i + 4);
    f16x8 o;
    #pragma unroll
    for (int j = 0; j < 4; ++j) { o[j] = (_Float16)a[j]; o[j + 4] = (_Float16)b[j]; }
    *(f16x8*)(out + i) = o;
}

// ---------------- fp32 in [R][C] -> fp16 out[c][r] (convert + transpose) ----
__global__ __launch_bounds__(256) void k_cvtT(
    const float* __restrict__ in, _Float16* __restrict__ out, int R, int C) {
    __shared__ _Float16 tile[32][33];
    int c0 = blockIdx.x * 32, r0 = blockIdx.y * 32;
    int tx = threadIdx.x & 31, ty = threadIdx.x >> 5;
    #pragma unroll
    for (int i = ty; i < 32; i += 8)
        tile[i][tx] = (_Float16)in[(size_t)(r0 + i) * C + c0 + tx];
    __syncthreads();
    #pragma unroll
    for (int i = ty; i < 32; i += 8)
        out[(size_t)(c0 + i) * R + r0 + tx] = tile[tx][i];
}

// ---------------- fp16 transpose: out[c][r] = in[r][c], in is [R][C] --------
__global__ __launch_bounds__(256) void k_transpose16(
    const _Float16* __restrict__ in, _Float16* __restrict__ out, int R, int C) {
    __shared__ _Float16 tile[32][33];
    int c0 = blockIdx.x * 32, r0 = blockIdx.y * 32;
    int tx = threadIdx.x & 31, ty = threadIdx.x >> 5;
    #pragma unroll
    for (int i = ty; i < 32; i += 8)
        tile[i][tx] = in[(size_t)(r0 + i) * C + c0 + tx];
    __syncthreads();
    #pragma unroll
    for (int i = ty; i < 32; i += 8)
        out[(size_t)(c0 + i) * R + r0 + tx] = tile[tx][i];
}

// ---------------- m97-style fp16 GEMM, C = A @ Bt^T -------------------------
// A: [M,K] fp16 row-major, Bt: [N,K] fp16 row-major. BM=128 fixed.
// LDS k-segment swizzle: slot s of row r holds k-seg (s - (r>>1))&3, so
// fragment reads alias banks only 2-way (free) instead of 8-way.
// OM: 0 = fp32 store, 1 = fp16 store, 2 = fp32 + residual, 3 = split-K fp32
//     partials (blockIdx.z selects K-chunk and partial buffer; K = chunk len)
template<int OM, int BN>
__global__ __launch_bounds__(256, 2) void k_gemm_bt(
    const _Float16* __restrict__ A, int lda,
    const _Float16* __restrict__ Bt, int ldb,
    void* __restrict__ Cp, int ldc, int K,
    const float* __restrict__ R) {
    constexpr int BM  = 128;
    constexpr int NI  = BN / 32;          // 16x16 tiles per wave in N
    constexpr int NCH = (BM + BN) / 16;   // 1KB staging chunks
    __shared__ _Float16 As[BM * 32];
    __shared__ _Float16 Bs[BN * 32];
    if constexpr (OM == 3) {
        A  += (size_t)blockIdx.z * K;
        Bt += (size_t)blockIdx.z * K;
        Cp = (void*)((float*)Cp + (size_t)blockIdx.z * 8192 * 512);
    }
    const int row0 = blockIdx.y * BM, col0 = blockIdx.x * BN;
    const int tid = threadIdx.x, w = tid >> 6, lane = tid & 63;
    const int wm = w >> 1, wn = w & 1;
    const int lrow = lane & 15, quad = lane >> 4;
    const int r16 = lane >> 2;            // row within 16-row chunk
    // swizzled source k-seg for this lane's LDS slot (slot seg = lane&3)
    const int kc  = (((lane & 3) - ((lane >> 3) & 3)) & 3) * 8;
    const int sqA = ((quad + (lrow >> 1)) & 3) * 8;  // reader seg offset
    f32x4 acc[4][NI] = {};

    for (int k0 = 0; k0 < K; k0 += 32) {
        #pragma unroll
        for (int i = 0; i < NCH / 4; ++i) {
            int c = w + i * 4;            // wave-uniform chunk id
            if (c < BM / 16) {
                gload_lds16(A + (size_t)(row0 + c * 16 + r16) * lda + (k0 + kc),
                            As + c * 512);
            } else {
                int c2 = c - BM / 16;
                gload_lds16(Bt + (size_t)(col0 + c2 * 16 + r16) * ldb + (k0 + kc),
                            Bs + c2 * 512);
            }
        }
        __syncthreads();
        f16x8 af[4], bfr[NI];
        #pragma unroll
        for (int i = 0; i < 4; ++i)
            af[i] = *(const f16x8*)(As + (wm * 64 + i * 16 + lrow) * 32 + sqA);
        #pragma unroll
        for (int i = 0; i < NI; ++i)
            bfr[i] = *(const f16x8*)(Bs + (wn * (BN / 2) + i * 16 + lrow) * 32 + sqA);
        #pragma unroll
        for (int mi = 0; mi < 4; ++mi)
            #pragma unroll
            for (int ni = 0; ni < NI; ++ni)
                acc[mi][ni] = __builtin_amdgcn_mfma_f32_16x16x32_f16(
                    af[mi], bfr[ni], acc[mi][ni], 0, 0, 0);
        __syncthreads();
    }
    // epilogue: C/D layout col=lane&15, row=quad*4+reg
    #pragma unroll
    for (int mi = 0; mi < 4; ++mi) {
        #pragma unroll
        for (int ni = 0; ni < NI; ++ni) {
            int col = col0 + wn * (BN / 2) + ni * 16 + lrow;
            #pragma unroll
            for (int r = 0; r < 4; ++r) {
                int row = row0 + wm * 64 + mi * 16 + quad * 4 + r;
                float v = acc[mi][ni][r];
                if constexpr (OM == 1) {
                    ((_Float16*)Cp)[(size_t)row * ldc + col] = (_Float16)v;
                } else if constexpr (OM == 2) {
                    v += R[(size_t)row * ldc + col];
                    ((float*)Cp)[(size_t)row * ldc + col] = v;
                } else {
                    ((float*)Cp)[(size_t)row * ldc + col] = v;
                }
            }
        }
    }
}

// ---------------- split WhWs -> Wh(fp16), T = tanh(Wh+Ws+bias) (fp16) -------
__global__ __launch_bounds__(256) void k_tanh_split(
    const float* __restrict__ WhWs, _Float16* __restrict__ T,
    _Float16* __restrict__ Wh,
    const float* __restrict__ aw, const float* __restrict__ ab) {
    int i = blockIdx.x * 256 + threadIdx.x;      // over 8192*512
    float bias = aw[0] + ab[0];
    int row = i >> 9, col = i & 511;
    float wh  = WhWs[(size_t)row * 1024 + col];
    float wsv = WhWs[(size_t)row * 1024 + 512 + col];
    Wh[i] = (_Float16)wh;
    T[i]  = (_Float16)tanhf(wh + wsv + bias);
}

// ---------------- row softmax in place: S fp16 -> P fp16 --------------------
__global__ __launch_bounds__(256) void k_softmax_rows(
    _Float16* __restrict__ S, int N) {
    const int row = blockIdx.x;
    _Float16* prow = S + (size_t)row * N;
    const int t = threadIdx.x;
    float v[32];
    #pragma unroll
    for (int it = 0; it < 4; ++it) {
        f16x8 h = *(const f16x8*)(prow + (it * 256 + t) * 8);
        #pragma unroll
        for (int j = 0; j < 8; ++j) v[it * 8 + j] = (float)h[j];
    }
    float m = v[0];
    #pragma unroll
    for (int j = 1; j < 32; ++j) m = fmaxf(m, v[j]);
    #pragma unroll
    for (int off = 32; off > 0; off >>= 1) m = fmaxf(m, __shfl_xor(m, off));
    __shared__ float red[8];
    const int wid = t >> 6, lane = t & 63;
    if (lane == 0) red[wid] = m;
    __syncthreads();
    m = fmaxf(fmaxf(red[0], red[1]), fmaxf(red[2], red[3]));
    float l = 0.f;
    #pragma unroll
    for (int j = 0; j < 32; ++j) l += __expf(v[j] - m);
    #pragma unroll
    for (int off = 32; off > 0; off >>= 1) l += __shfl_xor(l, off);
    if (lane == 0) red[4 + wid] = l;
    __syncthreads();
    float rl = 1.f / (red[4] + red[5] + red[6] + red[7]);
    #pragma unroll
    for (int it = 0; it < 4; ++it) {
        f16x8 pk;
        #pragma unroll
        for (int j = 0; j < 8; ++j)
            pk[j] = (_Float16)(__expf(v[it * 8 + j] - m) * rl);
        *(f16x8*)(prow + (it * 256 + t) * 8) = pk;
    }
}

// ---------------- reduce split-K partials + residual ------------------------
__global__ __launch_bounds__(256) void k_reduce_residual(
    const float* __restrict__ part, const float* __restrict__ X,
    float* __restrict__ outf) {
    int i = (blockIdx.x * 256 + threadIdx.x) * 4;
    f32x4 a = *(const f32x4*)(part + i);
    f32x4 b = *(const f32x4*)(part + (size_t)8192 * 512 + i);
    f32x4 x = *(const f32x4*)(X + i);
    f32x4 o;
    #pragma unroll
    for (int j = 0; j < 4; ++j) o[j] = a[j] + b[j] + x[j];
    *(f32x4*)(outf + i) = o;
}

// ---------------- per-column sum / sumsq over rows (atomics) ----------------
__global__ __launch_bounds__(256) void k_col_stats(
    const float* __restrict__ outf, float* __restrict__ colsum,
    float* __restrict__ colsq) {
    int t = threadIdx.x;
    int r0 = blockIdx.x * 128;
    float s0 = 0, q0 = 0, s1 = 0, q1 = 0;
    for (int r = 0; r < 128; ++r) {
        const float* p = outf + (size_t)(r0 + r) * 512;
        float a = p[t], b = p[t + 256];
        s0 += a; q0 += a * a; s1 += b; q1 += b * b;
    }
    atomicAdd(&colsum[t], s0);       atomicAdd(&colsq[t], q0);
    atomicAdd(&colsum[t + 256], s1); atomicAdd(&colsq[t + 256], q1);
}

// ---------------- batchnorm (no affine) + leaky relu -> fp32 ----------------
__global__ __launch_bounds__(256) void k_bn_lrelu(
    const float* __restrict__ outf, const float* __restrict__ colsum,
    const float* __restrict__ colsq, float* __restrict__ out) {
    int i = blockIdx.x * 256 + threadIdx.x;
    int c = i & 511;
    constexpr float rN = 1.f / 8192.f;
    float mean = colsum[c] * rN;
    float var  = colsq[c] * rN - mean * mean;
    float y = (outf[i] - mean) * rsqrtf(var + 1e-5f);
    y = (y >= 0.f) ? y : 0.01f * y;
    out[i] = y;
}

extern "C" void kernel_launch(void* const* d_in, const int* in_sizes, int n_in,
                              void* d_out, int out_size, void* d_ws, size_t ws_size,
                              hipStream_t stream) {
    const float* X  = (const float*)d_in[0];  // [8192,512] fp32
    // d_in[1] = adj, unused
    const float* W  = (const float*)d_in[2];  // [512,1024] fp32
    const float* aw = (const float*)d_in[3];
    const float* ab = (const float*)d_in[4];
    float* out = (float*)d_out;               // [8192,512] fp32

    char* ws = (char*)d_ws;
    _Float16* Xh   = (_Float16*)(ws + 0x0);         //  8 MB  [8192,512]
    _Float16* Wt   = (_Float16*)(ws + 0x800000);    //  1 MB  W^T [1024,512]
    float*    WhWs = (float*)   (ws + 0x900000);    // 32 MB  [8192,1024] fp32; reused as split-K partials
    _Float16* T    = (_Float16*)(ws + 0x2900000);   //  8 MB  [8192,512]
    _Float16* Whh  = (_Float16*)(ws + 0x3100000);   //  8 MB  [8192,512]
    _Float16* WhT  = (_Float16*)(ws + 0x3900000);   //  8 MB  [512,8192]
    _Float16* S    = (_Float16*)(ws + 0x4100000);   // 128 MB [8192,8192] fp16
    float*    outf = (float*)   (ws + 0xC100000);   // 16 MB  [8192,512] fp32
    float*    cs   = (float*)   (ws + 0xD100000);   //  2 KB
    float*    cq   = (float*)   (ws + 0xD100800);   //  2 KB
    float*    part = WhWs;                          // 32 MB: 2 x [8192,512] fp32

    // 0. Xh = fp16(X)
    k_cvt_x<<<dim3((8192 * 512) / 2048), 256, 0, stream>>>(X, Xh);
    // 1. Wt = fp16(W^T)  (W is [512, 1024])
    k_cvtT<<<dim3(1024 / 32, 512 / 32), 256, 0, stream>>>(W, Wt, 512, 1024);
    // 2. WhWs = Xh @ W  (fp32 out)  M=8192 N=1024 K=512
    k_gemm_bt<0, 128><<<dim3(1024 / 128, 8192 / 128), 256, 0, stream>>>(
        Xh, 512, Wt, 512, WhWs, 1024, 512, nullptr);
    // 3. Whh (fp16) and T = tanh(Wh + Ws + bias) (fp16)
    k_tanh_split<<<dim3((8192 * 512) / 256), 256, 0, stream>>>(WhWs, T, Whh, aw, ab);
    // 4. WhT = Whh^T
    k_transpose16<<<dim3(512 / 32, 8192 / 32), 256, 0, stream>>>(Whh, WhT, 8192, 512);
    // 5. S = T @ Whh^T  (fp16 out)  M=8192 N=8192 K=512
    k_gemm_bt<1, 128><<<dim3(8192 / 128, 8192 / 128), 256, 0, stream>>>(
        T, 512, Whh, 512, S, 8192, 512, nullptr);
    // 6. row softmax in place: S -> P (fp16)
    k_softmax_rows<<<dim3(8192), 256, 0, stream>>>(S, 8192);
    // 7. split-K GEMM3: part[z] = P @ Wh (K-chunks of 4096), BN=128, 512 blocks
    k_gemm_bt<3, 128><<<dim3(512 / 128, 8192 / 128, 2), 256, 0, stream>>>(
        S, 8192, WhT, 8192, part, 512, 4096, nullptr);
    // 7b. outf = part0 + part1 + X
    k_reduce_residual<<<dim3((8192 * 512) / 1024), 256, 0, stream>>>(part, X, outf);
    // 8-9. batch norm stats + normalize + leaky relu
    hipMemsetAsync(cs, 0, 4096, stream);
    k_col_stats<<<dim3(64), 256, 0, stream>>>(outf, cs, cq);
    k_bn_lrelu<<<dim3((8192 * 512) / 256), 256, 0, stream>>>(outf, cs, cq, out);
}